// Round 1
// baseline (362.615 us; speedup 1.0000x reference)
//
#include <hip/hip_runtime.h>
#include <stdint.h>

#define N_IMG 32
#define P_TOT 8400
#define NCLS 80
#define NMS_PRE 1000
#define MAXOUT 100
#define SCORE_THRF 0.01f
#define NMS_THRF 0.65f
#define SORT_N 16384

// Level layout: p in [0,6400): 80x80 s=8 ; [6400,8000): 40x40 s=16 ; [8000,8400): 20x20 s=32

__device__ __forceinline__ float sigmoidf_(float x) { return 1.0f / (1.0f + expf(-x)); }

// ---------------- Kernel 1: scores -> sort keys ----------------
__global__ __launch_bounds__(256) void k_score(
    const float* __restrict__ cls0, const float* __restrict__ cls1, const float* __restrict__ cls2,
    const float* __restrict__ obj0, const float* __restrict__ obj1, const float* __restrict__ obj2,
    uint64_t* __restrict__ keys)
{
    int gid = blockIdx.x * blockDim.x + threadIdx.x;
    if (gid >= N_IMG * P_TOT) return;
    int n = gid / P_TOT, p = gid - n * P_TOT;

    const float* cl; const float* ob; int HW, q;
    if (p < 6400)      { cl = cls0; ob = obj0; HW = 6400; q = p; }
    else if (p < 8000) { cl = cls1; ob = obj1; HW = 1600; q = p - 6400; }
    else               { cl = cls2; ob = obj2; HW = 400;  q = p - 8000; }

    const float* cbase = cl + (size_t)n * NCLS * HW + q;
    // argmax over sigmoid(cls) (first max wins, like jnp.argmax)
    float best = -1.0f; int bc = 0;
    #pragma unroll 4
    for (int c = 0; c < NCLS; ++c) {
        float s = sigmoidf_(cbase[(size_t)c * HW]);
        if (s > best) { best = s; bc = c; }
    }
    float so = sigmoidf_(ob[(size_t)n * HW + q]);
    float sc = __fmul_rn(best, so);
    float masked = (sc >= SCORE_THRF) ? sc : -1.0f;

    // descending-order sortable key; ties broken by ascending p (lax.top_k semantics)
    uint32_t u = __float_as_uint(masked);
    uint32_t ord = (u & 0x80000000u) ? ~u : (u | 0x80000000u); // ascending order map
    uint32_t dk = ~ord;                                         // descending
    keys[gid] = ((uint64_t)dk << 32) | (uint32_t)((p << 8) | bc);
}

// ---------------- Kernel 2: per-image bitonic top-1000 + box decode ----------------
__global__ __launch_bounds__(1024) void k_topk(
    const uint64_t* __restrict__ keys,
    const float* __restrict__ reg0, const float* __restrict__ reg1, const float* __restrict__ reg2,
    float4* __restrict__ selA, float4* __restrict__ selB)
{
    __shared__ uint64_t sh[SORT_N];   // 128 KiB
    int n = blockIdx.x, tid = threadIdx.x;

    for (int t = tid; t < SORT_N; t += 1024)
        sh[t] = (t < P_TOT) ? keys[(size_t)n * P_TOT + t] : ~0ull;
    __syncthreads();

    // ascending bitonic sort => score descending, index ascending on ties
    for (int k = 2; k <= SORT_N; k <<= 1) {
        for (int j = k >> 1; j > 0; j >>= 1) {
            for (int t = tid; t < SORT_N; t += 1024) {
                int ixj = t ^ j;
                if (ixj > t) {
                    uint64_t a = sh[t], b = sh[ixj];
                    bool up = (t & k) == 0;
                    if (up ? (a > b) : (a < b)) { sh[t] = b; sh[ixj] = a; }
                }
            }
            __syncthreads();
        }
    }

    // decode top-1000, recompute boxes exactly like reference (mul/add separately rounded)
    float4 bx = make_float4(0.f, 0.f, 0.f, 0.f);
    float scm = 0.f, labf = 0.f, m = 0.f;
    if (tid < NMS_PRE) {
        uint64_t key = sh[tid];
        uint32_t low = (uint32_t)key;
        int lab = (int)(low & 0xFFu);
        int p   = (int)(low >> 8);
        uint32_t ord = ~(uint32_t)(key >> 32);
        uint32_t fb = (ord & 0x80000000u) ? (ord ^ 0x80000000u) : ~ord;
        scm = __uint_as_float(fb);

        const float* rg; int HW, q, W; float s;
        if (p < 6400)      { rg = reg0; HW = 6400; q = p;        W = 80; s = 8.f; }
        else if (p < 8000) { rg = reg1; HW = 1600; q = p - 6400; W = 40; s = 16.f; }
        else               { rg = reg2; HW = 400;  q = p - 8000; W = 20; s = 32.f; }

        float px = (float)(q % W) * s;   // exact
        float py = (float)(q / W) * s;   // exact
        const float* rb = rg + (size_t)n * 4 * HW + q;
        float dx = rb[0], dy = rb[HW], dw = rb[2 * HW], dh = rb[3 * HW];
        float cx = __fadd_rn(__fmul_rn(dx, s), px);
        float cy = __fadd_rn(__fmul_rn(dy, s), py);
        float hw = __fmul_rn(__fmul_rn(expf(dw), s), 0.5f);
        float hh = __fmul_rn(__fmul_rn(expf(dh), s), 0.5f);
        bx.x = __fsub_rn(cx, hw); bx.y = __fsub_rn(cy, hh);
        bx.z = __fadd_rn(cx, hw); bx.w = __fadd_rn(cy, hh);
        labf = (float)lab;
        m = fmaxf(fmaxf(fabsf(bx.x), fabsf(bx.y)), fmaxf(fabsf(bx.z), fabsf(bx.w)));
    }

    // block max-reduce of |b| over the 1000 gathered boxes
    for (int o = 32; o > 0; o >>= 1) m = fmaxf(m, __shfl_xor(m, o));
    __syncthreads();                       // all decodes done before LDS reuse
    float* scratch = (float*)&sh[SORT_N - 64];
    if ((tid & 63) == 0) scratch[tid >> 6] = m;
    __syncthreads();
    if (tid == 0) {
        float g = scratch[0];
        for (int w = 1; w < 16; ++w) g = fmaxf(g, scratch[w]);
        scratch[16] = g;
    }
    __syncthreads();
    float gmax = scratch[16];

    if (tid < NMS_PRE) {
        float off = __fmul_rn(labf, __fadd_rn(gmax, 1.0f)); // lab * (max|b| + 1)
        selA[n * NMS_PRE + tid] = bx;                        // raw box (output)
        selB[n * NMS_PRE + tid] = make_float4(scm, labf, off, 0.f);
    }
}

// ---------------- Kernel 3: greedy NMS (1 wave / image) + output ----------------
__global__ __launch_bounds__(64) void k_nms(
    const float4* __restrict__ selA, const float4* __restrict__ selB,
    float* __restrict__ out)
{
    __shared__ float4 kb[MAXOUT];   // kept offset-boxes
    __shared__ float  ka[MAXOUT];   // kept areas (of offset boxes)
    int n = blockIdx.x, lane = threadIdx.x;
    float* ob = out;                          // [32*100*4]
    float* os = out + N_IMG * MAXOUT * 4;     // [32*100]
    float* ol = os + N_IMG * MAXOUT;          // [32*100] labels as float

    int count = 0;
    for (int i = 0; i < NMS_PRE && count < MAXOUT; ++i) {
        float4 b    = selA[n * NMS_PRE + i];
        float4 meta = selB[n * NMS_PRE + i];
        if (!(meta.x >= SCORE_THRF)) break;   // sorted: all remaining invalid

        float off = meta.z;
        float x1 = __fadd_rn(b.x, off), y1 = __fadd_rn(b.y, off);
        float x2 = __fadd_rn(b.z, off), y2 = __fadd_rn(b.w, off);
        float area = __fmul_rn(__fsub_rn(x2, x1), __fsub_rn(y2, y1));

        bool sup = false;
        for (int j = lane; j < count; j += 64) {
            float4 kbj = kb[j];
            float ltx = fmaxf(x1, kbj.x), lty = fmaxf(y1, kbj.y);
            float rbx = fminf(x2, kbj.z), rby = fminf(y2, kbj.w);
            float w = fmaxf(__fsub_rn(rbx, ltx), 0.f);
            float h = fmaxf(__fsub_rn(rby, lty), 0.f);
            float inter = __fmul_rn(w, h);
            float denom = __fadd_rn(__fsub_rn(__fadd_rn(ka[j], area), inter), 1e-9f);
            if (inter / denom > NMS_THRF) sup = true;
        }
        if (__ballot(sup) == 0ull) {   // kept (uniform decision)
            if (lane == 0) {
                kb[count] = make_float4(x1, y1, x2, y2);
                ka[count] = area;
                int o4 = (n * MAXOUT + count) * 4;
                ob[o4 + 0] = b.x; ob[o4 + 1] = b.y; ob[o4 + 2] = b.z; ob[o4 + 3] = b.w;
                os[n * MAXOUT + count] = meta.x;
                ol[n * MAXOUT + count] = meta.y;
            }
            count++;
        }
        __syncthreads();  // make kept-box LDS write visible
    }
    // pad remaining slots: boxes 0, score 0, label -1
    for (int mi = count + lane; mi < MAXOUT; mi += 64) {
        int o4 = (n * MAXOUT + mi) * 4;
        ob[o4 + 0] = 0.f; ob[o4 + 1] = 0.f; ob[o4 + 2] = 0.f; ob[o4 + 3] = 0.f;
        os[n * MAXOUT + mi] = 0.f;
        ol[n * MAXOUT + mi] = -1.f;
    }
}

extern "C" void kernel_launch(void* const* d_in, const int* in_sizes, int n_in,
                              void* d_out, int out_size, void* d_ws, size_t ws_size,
                              hipStream_t stream)
{
    const float* cls0 = (const float*)d_in[0];
    const float* cls1 = (const float*)d_in[1];
    const float* cls2 = (const float*)d_in[2];
    const float* reg0 = (const float*)d_in[3];
    const float* reg1 = (const float*)d_in[4];
    const float* reg2 = (const float*)d_in[5];
    const float* obj0 = (const float*)d_in[6];
    const float* obj1 = (const float*)d_in[7];
    const float* obj2 = (const float*)d_in[8];

    uint64_t* keys = (uint64_t*)d_ws;                                   // 32*8400*8 B
    float4* selA = (float4*)((char*)d_ws + (size_t)N_IMG * P_TOT * 8);  // 32*1000*16 B
    float4* selB = selA + N_IMG * NMS_PRE;                              // 32*1000*16 B
    float* out = (float*)d_out;

    k_score<<<(N_IMG * P_TOT + 255) / 256, 256, 0, stream>>>(
        cls0, cls1, cls2, obj0, obj1, obj2, keys);
    k_topk<<<N_IMG, 1024, 0, stream>>>(keys, reg0, reg1, reg2, selA, selB);
    k_nms<<<N_IMG, 64, 0, stream>>>(selA, selB, out);
}

// Round 2
// 110.188 us; speedup vs baseline: 3.2909x; 3.2909x over previous
//
#include <hip/hip_runtime.h>
#include <stdint.h>

#define N_IMG 32
#define P_TOT 8400
#define NCLS 80
#define NMS_PRE 1000
#define MAXOUT 100
#define SCORE_THRF 0.01f
#define NMS_THRF 0.65f
#define NBIN 16384      // 14-bit bins: exponent(8) + top-6 mantissa of descending key
#define CAND_N 2048

// Level layout: p in [0,6400): 80x80 s=8 ; [6400,8000): 40x40 s=16 ; [8000,8400): 20x20 s=32

__device__ __forceinline__ float sigmoidf_(float x) { return 1.0f / (1.0f + expf(-x)); }

// ---------------- Kernel 1: scores -> sort keys ----------------
__global__ __launch_bounds__(256) void k_score(
    const float* __restrict__ cls0, const float* __restrict__ cls1, const float* __restrict__ cls2,
    const float* __restrict__ obj0, const float* __restrict__ obj1, const float* __restrict__ obj2,
    uint64_t* __restrict__ keys)
{
    int gid = blockIdx.x * blockDim.x + threadIdx.x;
    if (gid >= N_IMG * P_TOT) return;
    int n = gid / P_TOT, p = gid - n * P_TOT;

    const float* cl; const float* ob; int HW, q;
    if (p < 6400)      { cl = cls0; ob = obj0; HW = 6400; q = p; }
    else if (p < 8000) { cl = cls1; ob = obj1; HW = 1600; q = p - 6400; }
    else               { cl = cls2; ob = obj2; HW = 400;  q = p - 8000; }

    const float* cbase = cl + (size_t)n * NCLS * HW + q;
    // argmax over sigmoid(cls) (first max wins, like jnp.argmax)
    float best = -1.0f; int bc = 0;
    #pragma unroll 4
    for (int c = 0; c < NCLS; ++c) {
        float s = sigmoidf_(cbase[(size_t)c * HW]);
        if (s > best) { best = s; bc = c; }
    }
    float so = sigmoidf_(ob[(size_t)n * HW + q]);
    float sc = __fmul_rn(best, so);
    float masked = (sc >= SCORE_THRF) ? sc : -1.0f;

    // descending-order sortable key; ties broken by ascending p (lax.top_k semantics)
    uint32_t u = __float_as_uint(masked);
    uint32_t ord = (u & 0x80000000u) ? ~u : (u | 0x80000000u); // ascending order map
    uint32_t dk = ~ord;                                         // descending (valid => top bit 0)
    keys[gid] = ((uint64_t)dk << 32) | (uint32_t)((p << 8) | bc);
}

// ---------------- Kernel 2: histogram-select top-1000 + sort-2048 + decode ----------------
__global__ __launch_bounds__(1024) void k_select(
    const uint64_t* __restrict__ keys,
    const float* __restrict__ reg0, const float* __restrict__ reg1, const float* __restrict__ reg2,
    float4* __restrict__ selA, float4* __restrict__ selB)
{
    __shared__ uint32_t hist[NBIN];       // 64 KiB
    __shared__ uint64_t cand[CAND_N];     // 16 KiB
    __shared__ uint32_t wsum[16];
    __shared__ uint32_t woff[17];
    __shared__ uint32_t s_misc[2];        // [0]=cutoff bin, [1]=cand count
    __shared__ float    fsh[17];

    int n = blockIdx.x, tid = threadIdx.x;

    for (int t = tid; t < NBIN; t += 1024) hist[t] = 0;
    for (int t = tid; t < CAND_N; t += 1024) cand[t] = ~0ull;
    if (tid == 0) { s_misc[0] = 0; s_misc[1] = 0; }
    __syncthreads();

    // histogram valid keys; cache keys in registers for the compaction pass
    uint64_t rk[9];
    #pragma unroll
    for (int it = 0; it < 9; ++it) {
        int t = tid + it * 1024;
        uint64_t k = ~0ull;
        if (t < P_TOT) {
            k = keys[(size_t)n * P_TOT + t];
            uint32_t dk = (uint32_t)(k >> 32);
            if (!(dk & 0x80000000u)) atomicAdd(&hist[dk >> 17], 1u);
        }
        rk[it] = k;
    }
    __syncthreads();

    // block scan over bins: thread i owns bins [16i, 16i+16)
    uint32_t part = 0;
    #pragma unroll
    for (int b = 0; b < 16; ++b) part += hist[tid * 16 + b];
    uint32_t inc = part;
    #pragma unroll
    for (int o = 1; o < 64; o <<= 1) {
        uint32_t v = __shfl_up(inc, o);
        if ((tid & 63) >= o) inc += v;
    }
    if ((tid & 63) == 63) wsum[tid >> 6] = inc;
    __syncthreads();
    if (tid == 0) {
        uint32_t acc = 0;
        #pragma unroll
        for (int w = 0; w < 16; ++w) { woff[w] = acc; acc += wsum[w]; }
        woff[16] = acc;
    }
    __syncthreads();
    uint32_t total = woff[16];
    uint32_t target = total < (uint32_t)NMS_PRE ? total : (uint32_t)NMS_PRE;
    uint32_t exc = woff[tid >> 6] + (inc - part);   // exclusive prefix of my chunk
    if (total > 0 && exc < target && exc + part >= target) {
        uint32_t c = exc; int b = 0;
        #pragma unroll
        for (int bb = 0; bb < 16; ++bb) {
            c += hist[tid * 16 + bb];
            if (c >= target) { b = bb; break; }
        }
        s_misc[0] = (uint32_t)(tid * 16 + b);
    }
    __syncthreads();
    uint32_t Bcut = s_misc[0];

    // compact candidates (bins <= Bcut) from the register cache
    #pragma unroll
    for (int it = 0; it < 9; ++it) {
        uint64_t k = rk[it];
        uint32_t dk = (uint32_t)(k >> 32);
        if (!(dk & 0x80000000u) && (dk >> 17) <= Bcut) {
            uint32_t slot = atomicAdd(&s_misc[1], 1u);
            if (slot < CAND_N) cand[slot] = k;
        }
    }
    __syncthreads();

    // bitonic sort 2048 (ascending key = descending score, index-tiebroken)
    for (int k = 2; k <= CAND_N; k <<= 1) {
        for (int j = k >> 1; j > 0; j >>= 1) {
            int i = ((tid & ~(j - 1)) << 1) | (tid & (j - 1));
            int ixj = i | j;
            uint64_t a = cand[i], b = cand[ixj];
            bool up = (i & k) == 0;
            if (up ? (a > b) : (a < b)) { cand[i] = b; cand[ixj] = a; }
            __syncthreads();
        }
    }

    // decode top-1000 exactly like reference (mul/add separately rounded)
    float4 bx = make_float4(0.f, 0.f, 0.f, 0.f);
    float scm = -1.0f, labf = 0.f, m = 0.f;
    if (tid < NMS_PRE) {
        uint64_t key = cand[tid];
        uint32_t dk = (uint32_t)(key >> 32);
        if (!(dk & 0x80000000u)) {
            uint32_t low = (uint32_t)key;
            int lab = (int)(low & 0xFFu);
            int p   = (int)(low >> 8);
            uint32_t ord = ~dk;
            scm = __uint_as_float(ord ^ 0x80000000u);   // valid => positive float

            const float* rg; int HW, q, W; float s;
            if (p < 6400)      { rg = reg0; HW = 6400; q = p;        W = 80; s = 8.f; }
            else if (p < 8000) { rg = reg1; HW = 1600; q = p - 6400; W = 40; s = 16.f; }
            else               { rg = reg2; HW = 400;  q = p - 8000; W = 20; s = 32.f; }

            float px = (float)(q % W) * s;   // exact
            float py = (float)(q / W) * s;   // exact
            const float* rb = rg + (size_t)n * 4 * HW + q;
            float dx = rb[0], dy = rb[HW], dw = rb[2 * HW], dh = rb[3 * HW];
            float cx = __fadd_rn(__fmul_rn(dx, s), px);
            float cy = __fadd_rn(__fmul_rn(dy, s), py);
            float hw = __fmul_rn(__fmul_rn(expf(dw), s), 0.5f);
            float hh = __fmul_rn(__fmul_rn(expf(dh), s), 0.5f);
            bx.x = __fsub_rn(cx, hw); bx.y = __fsub_rn(cy, hh);
            bx.z = __fadd_rn(cx, hw); bx.w = __fadd_rn(cy, hh);
            labf = (float)lab;
            m = fmaxf(fmaxf(fabsf(bx.x), fabsf(bx.y)), fmaxf(fabsf(bx.z), fabsf(bx.w)));
        }
    }

    // block max-reduce of |b| over the 1000 gathered boxes
    #pragma unroll
    for (int o = 32; o > 0; o >>= 1) m = fmaxf(m, __shfl_xor(m, o));
    if ((tid & 63) == 0) fsh[tid >> 6] = m;
    __syncthreads();
    if (tid == 0) {
        float g = fsh[0];
        #pragma unroll
        for (int w = 1; w < 16; ++w) g = fmaxf(g, fsh[w]);
        fsh[16] = g;
    }
    __syncthreads();
    float gmax = fsh[16];

    if (tid < NMS_PRE) {
        float off = __fmul_rn(labf, __fadd_rn(gmax, 1.0f)); // lab * (max|b| + 1)
        selA[n * NMS_PRE + tid] = bx;                        // raw box (output)
        selB[n * NMS_PRE + tid] = make_float4(scm, labf, off, 0.f);
    }
}

// ---------------- Kernel 3: greedy NMS (1 wave / image, LDS-preloaded) ----------------
__global__ __launch_bounds__(64) void k_nms(
    const float4* __restrict__ selA, const float4* __restrict__ selB,
    float* __restrict__ out)
{
    __shared__ float4 sA[NMS_PRE];   // 16000 B
    __shared__ float4 sB[NMS_PRE];   // 16000 B
    __shared__ float4 kb[MAXOUT];    // kept offset-boxes
    __shared__ float  ka[MAXOUT];    // kept areas (of offset boxes)
    int n = blockIdx.x, lane = threadIdx.x;
    float* ob = out;                          // [32*100*4]
    float* os = out + N_IMG * MAXOUT * 4;     // [32*100]
    float* ol = os + N_IMG * MAXOUT;          // [32*100] labels as float

    for (int t = lane; t < NMS_PRE; t += 64) {
        sA[t] = selA[n * NMS_PRE + t];
        sB[t] = selB[n * NMS_PRE + t];
    }
    __syncthreads();

    int count = 0;
    for (int i = 0; i < NMS_PRE && count < MAXOUT; ++i) {
        float4 b    = sA[i];
        float4 meta = sB[i];
        if (!(meta.x >= SCORE_THRF)) break;   // sorted: all remaining invalid

        float off = meta.z;
        float x1 = __fadd_rn(b.x, off), y1 = __fadd_rn(b.y, off);
        float x2 = __fadd_rn(b.z, off), y2 = __fadd_rn(b.w, off);
        float area = __fmul_rn(__fsub_rn(x2, x1), __fsub_rn(y2, y1));

        bool sup = false;
        for (int j = lane; j < count; j += 64) {
            float4 kbj = kb[j];
            float ltx = fmaxf(x1, kbj.x), lty = fmaxf(y1, kbj.y);
            float rbx = fminf(x2, kbj.z), rby = fminf(y2, kbj.w);
            float w = fmaxf(__fsub_rn(rbx, ltx), 0.f);
            float h = fmaxf(__fsub_rn(rby, lty), 0.f);
            float inter = __fmul_rn(w, h);
            float denom = __fadd_rn(__fsub_rn(__fadd_rn(ka[j], area), inter), 1e-9f);
            if (inter / denom > NMS_THRF) sup = true;
        }
        if (__ballot(sup) == 0ull) {   // kept (uniform decision)
            if (lane == 0) {
                kb[count] = make_float4(x1, y1, x2, y2);
                ka[count] = area;
                int o4 = (n * MAXOUT + count) * 4;
                ob[o4 + 0] = b.x; ob[o4 + 1] = b.y; ob[o4 + 2] = b.z; ob[o4 + 3] = b.w;
                os[n * MAXOUT + count] = meta.x;
                ol[n * MAXOUT + count] = meta.y;
            }
            count++;
        }
        __syncthreads();  // make kept-box LDS write visible
    }
    // pad remaining slots: boxes 0, score 0, label -1
    for (int mi = count + lane; mi < MAXOUT; mi += 64) {
        int o4 = (n * MAXOUT + mi) * 4;
        ob[o4 + 0] = 0.f; ob[o4 + 1] = 0.f; ob[o4 + 2] = 0.f; ob[o4 + 3] = 0.f;
        os[n * MAXOUT + mi] = 0.f;
        ol[n * MAXOUT + mi] = -1.f;
    }
}

extern "C" void kernel_launch(void* const* d_in, const int* in_sizes, int n_in,
                              void* d_out, int out_size, void* d_ws, size_t ws_size,
                              hipStream_t stream)
{
    const float* cls0 = (const float*)d_in[0];
    const float* cls1 = (const float*)d_in[1];
    const float* cls2 = (const float*)d_in[2];
    const float* reg0 = (const float*)d_in[3];
    const float* reg1 = (const float*)d_in[4];
    const float* reg2 = (const float*)d_in[5];
    const float* obj0 = (const float*)d_in[6];
    const float* obj1 = (const float*)d_in[7];
    const float* obj2 = (const float*)d_in[8];

    uint64_t* keys = (uint64_t*)d_ws;                                   // 32*8400*8 B
    float4* selA = (float4*)((char*)d_ws + (size_t)N_IMG * P_TOT * 8);  // 32*1000*16 B
    float4* selB = selA + N_IMG * NMS_PRE;                              // 32*1000*16 B
    float* out = (float*)d_out;

    k_score<<<(N_IMG * P_TOT + 255) / 256, 256, 0, stream>>>(
        cls0, cls1, cls2, obj0, obj1, obj2, keys);
    k_select<<<N_IMG, 1024, 0, stream>>>(keys, reg0, reg1, reg2, selA, selB);
    k_nms<<<N_IMG, 64, 0, stream>>>(selA, selB, out);
}